// Round 1
// baseline (68.288 us; speedup 1.0000x reference)
//
#include <hip/hip_runtime.h>
#include <hip/hip_bf16.h>

#define BDIM 512

typedef __attribute__((ext_vector_type(8))) _Float16 f16x8;
typedef __attribute__((ext_vector_type(4))) float f32x4;

// Local windowed attention with RoPE.
// b=32, n=4096, d=64, WINDOW=128, look_backward=1 -> J=256 keys per window.
// One block per (batch, window): Q[128x64] x K/V[256x64].
// 512 threads = 8 waves; wave wv owns q-rows [16*wv, 16*wv+16).
__global__ __launch_bounds__(512, 1)
void la_kernel(const float* __restrict__ qg, const float* __restrict__ kg,
               const float* __restrict__ vg, float* __restrict__ outg)
{
    // +8 f16 row padding on Qs/Ks (stride 144B) and Vt/Ps (stride 528B):
    // breaks the 16-way bank conflict of power-of-2 strides on ds_read_b128.
    __shared__ _Float16 Qs[128][72];
    __shared__ _Float16 Ks[256][72];
    __shared__ _Float16 Vt[64][264];
    __shared__ _Float16 Ps[128][264];

    const int ww = blockIdx.x;   // window 0..31
    const int bb = blockIdx.y;   // batch  0..31
    const int tid = threadIdx.x;
    const bool w0 = (ww == 0);

    const size_t qbase = ((size_t)bb * 4096 + (size_t)ww * 128) * 64;
    const float NEG = -3.0e38f;
    const float NLT32 = -0.28782313662425572f; // -ln(10000)/32

    // ---------------- staging ----------------
    // Q: RoPE(t = 128+row) and * d^-0.5
    for (int task = tid; task < 1024; task += BDIM) {
        int row = task >> 3;
        int cb  = (task & 7) << 2;           // 0..28, f-index block
        const float* p = qg + qbase + (size_t)row * 64 + cb;
        float4 x1 = *(const float4*)p;
        float4 x2 = *(const float4*)(p + 32);
        const float* x1p = &x1.x;
        const float* x2p = &x2.x;
        float t = (float)(128 + row);
        #pragma unroll
        for (int u = 0; u < 4; ++u) {
            float invf = expf((float)(cb + u) * NLT32);
            float sn, cs;
            sincosf(t * invf, &sn, &cs);
            float a = x1p[u] * 0.125f;
            float b = x2p[u] * 0.125f;
            Qs[row][cb + u]      = (_Float16)(a * cs - b * sn);
            Qs[row][cb + u + 32] = (_Float16)(b * cs + a * sn);
        }
    }

    // K: RoPE(t = j), j in [0,256); source row (ww-1)*128 + j, pad -> 0 (masked anyway)
    for (int task = tid; task < 2048; task += BDIM) {
        int j  = task >> 3;
        int cb = (task & 7) << 2;
        int src = ww * 128 - 128 + j;
        float4 x1 = {0.f,0.f,0.f,0.f}, x2 = {0.f,0.f,0.f,0.f};
        if (src >= 0) {
            const float* p = kg + ((size_t)bb * 4096 + src) * 64 + cb;
            x1 = *(const float4*)p;
            x2 = *(const float4*)(p + 32);
        }
        const float* x1p = &x1.x;
        const float* x2p = &x2.x;
        float t = (float)j;
        #pragma unroll
        for (int u = 0; u < 4; ++u) {
            float invf = expf((float)(cb + u) * NLT32);
            float sn, cs;
            sincosf(t * invf, &sn, &cs);
            float a = x1p[u];
            float b = x2p[u];
            Ks[j][cb + u]      = (_Float16)(a * cs - b * sn);
            Ks[j][cb + u + 32] = (_Float16)(b * cs + a * sn);
        }
    }

    // V: transpose into Vt[d][j] (pad rows -> 0; their attn weight is exactly 0)
    for (int task = tid; task < 4096; task += BDIM) {
        int j  = task >> 4;
        int cb = (task & 15) << 2;
        int src = ww * 128 - 128 + j;
        float4 x = {0.f,0.f,0.f,0.f};
        if (src >= 0) {
            x = *(const float4*)(vg + ((size_t)bb * 4096 + src) * 64 + cb);
        }
        const float* xp = &x.x;
        #pragma unroll
        for (int u = 0; u < 4; ++u)
            Vt[cb + u][j] = (_Float16)xp[u];
    }

    __syncthreads();

    // ---------------- compute (per wave, no further cross-wave deps) ----------------
    const int wv   = tid >> 6;     // wave id 0..7 -> m-tile
    const int lane = tid & 63;
    const int g    = lane >> 4;    // 0..3 k-group
    const int c    = lane & 15;

    // Q A-fragments: row = lane&15 within m-tile, 8 contiguous k at 8*g
    const int rowA = wv * 16 + c;
    f16x8 qa0 = *(const f16x8*)&Qs[rowA][8 * g];
    f16x8 qa1 = *(const f16x8*)&Qs[rowA][32 + 8 * g];

    f32x4 acc[16];
    #pragma unroll
    for (int jt = 0; jt < 16; ++jt) acc[jt] = (f32x4){0.f, 0.f, 0.f, 0.f};

    // sim = Q K^T : 16 j-tiles x (K=64 -> 2 mfma steps)
    #pragma unroll
    for (int jt = 0; jt < 16; ++jt) {
        f16x8 kb0 = *(const f16x8*)&Ks[jt * 16 + c][8 * g];
        f16x8 kb1 = *(const f16x8*)&Ks[jt * 16 + c][32 + 8 * g];
        acc[jt] = __builtin_amdgcn_mfma_f32_16x16x32_f16(qa0, kb0, acc[jt], 0, 0, 0);
        acc[jt] = __builtin_amdgcn_mfma_f32_16x16x32_f16(qa1, kb1, acc[jt], 0, 0, 0);
    }

    // mask: C/D layout is col = lane&15, row = 4*(lane>>4)+reg  [HW-verified]
    #pragma unroll
    for (int jt = 0; jt < 16; ++jt) {
        int j = jt * 16 + c;
        #pragma unroll
        for (int r = 0; r < 4; ++r) {
            int i = wv * 16 + g * 4 + r;
            if ((j > i + 128) || (w0 && j < 128)) acc[jt][r] = NEG;
        }
    }

    // row softmax: rows of one q live in one 16-lane group -> shfl_xor 1,2,4,8
    float rcp[4];
    #pragma unroll
    for (int r = 0; r < 4; ++r) {
        int i = wv * 16 + g * 4 + r;
        float m = NEG;
        #pragma unroll
        for (int jt = 0; jt < 16; ++jt) m = fmaxf(m, acc[jt][r]);
        #pragma unroll
        for (int off = 1; off < 16; off <<= 1) m = fmaxf(m, __shfl_xor(m, off));
        float s = 0.f;
        #pragma unroll
        for (int jt = 0; jt < 16; ++jt) {
            float p = expf(acc[jt][r] - m);   // masked: exp(-3e38 - m) == 0 exactly
            s += p;
            Ps[i][jt * 16 + c] = (_Float16)p;
        }
        #pragma unroll
        for (int off = 1; off < 16; off <<= 1) s += __shfl_xor(s, off);
        rcp[r] = 1.0f / s;
    }

    // out = P V : 4 n-tiles x (K'=256 -> 8 mfma steps). P rows are wave-private.
    f32x4 accO[4];
    #pragma unroll
    for (int nt = 0; nt < 4; ++nt) accO[nt] = (f32x4){0.f, 0.f, 0.f, 0.f};

    #pragma unroll
    for (int s8 = 0; s8 < 8; ++s8) {
        f16x8 pa = *(const f16x8*)&Ps[wv * 16 + c][s8 * 32 + 8 * g];
        #pragma unroll
        for (int nt = 0; nt < 4; ++nt) {
            f16x8 vb = *(const f16x8*)&Vt[nt * 16 + c][s8 * 32 + 8 * g];
            accO[nt] = __builtin_amdgcn_mfma_f32_16x16x32_f16(pa, vb, accO[nt], 0, 0, 0);
        }
    }

    // epilogue: divide by row sum, store fp32
    float* op = outg + qbase;
    #pragma unroll
    for (int nt = 0; nt < 4; ++nt) {
        #pragma unroll
        for (int r = 0; r < 4; ++r) {
            int i = wv * 16 + g * 4 + r;
            op[(size_t)i * 64 + nt * 16 + c] = accO[nt][r] * rcp[r];
        }
    }
}

extern "C" void kernel_launch(void* const* d_in, const int* in_sizes, int n_in,
                              void* d_out, int out_size, void* d_ws, size_t ws_size,
                              hipStream_t stream) {
    (void)in_sizes; (void)n_in; (void)out_size; (void)d_ws; (void)ws_size;
    const float* q = (const float*)d_in[0];
    const float* k = (const float*)d_in[1];
    const float* v = (const float*)d_in[2];
    float* out = (float*)d_out;
    dim3 grid(32, 32);  // x = window, y = batch
    la_kernel<<<grid, BDIM, 0, stream>>>(q, k, v, out);
}

// Round 2
// 44.676 us; speedup vs baseline: 1.5285x; 1.5285x over previous
//
#include <hip/hip_runtime.h>
#include <hip/hip_bf16.h>

#define BDIM 512

typedef __attribute__((ext_vector_type(8))) _Float16 f16x8;
typedef __attribute__((ext_vector_type(4))) _Float16 f16x4;
typedef __attribute__((ext_vector_type(4))) float f32x4;

// Local windowed attention with RoPE. b=32, n=4096, d=64, WINDOW=128, 1 backward window.
// One block per (batch, window): Q[128x64] x K/V[256x64]. 512 threads = 8 waves,
// wave wv owns q-rows [16*wv, 16*wv+16).
// QK^T computed SWAPPED: D = mfma(K_frag, Q_frag) -> D[j][i] with i = lane&15.
// Each lane then holds P[i=c][j=16*jt+4*g+r] -> softmax needs only shfl_xor(16,32),
// and P feeds PV directly from registers (A-operand) with V read in the SAME
// (group,slot)->j permutation (dot product is invariant under a shared k-relabeling).
__global__ __launch_bounds__(512, 4)
void la_kernel(const float* __restrict__ qg, const float* __restrict__ kg,
               const float* __restrict__ vg, float* __restrict__ outg)
{
    __shared__ _Float16 Ks[256][72];   // row stride 144B -> 2-way bank alias (free)
    __shared__ _Float16 Vt[64][268];   // stride 536B -> ~2-way; 8B-aligned for b64

    const int ww = blockIdx.x;   // window
    const int bb = blockIdx.y;   // batch
    const int tid = threadIdx.x;
    const bool w0 = (ww == 0);
    const size_t qbase = ((size_t)bb * 4096 + (size_t)ww * 128) * 64;
    const float NEG = -3.0e38f;
    const float NLT32 = -0.28782313662425572f; // -ln(10000)/32

    const int wv = tid >> 6, lane = tid & 63, g = lane >> 4, c = lane & 15;

    // ---- per-lane Q load + RoPE (no LDS) ----
    const int qrow = wv * 16 + c;            // i in [0,128)
    f16x8 qa0, qa1;
    {
        const float* p = qg + qbase + (size_t)qrow * 64 + 8 * g;
        float4 a0 = *(const float4*)p;
        float4 a1 = *(const float4*)(p + 4);
        float4 b0 = *(const float4*)(p + 32);
        float4 b1 = *(const float4*)(p + 36);
        float ra[8] = {a0.x,a0.y,a0.z,a0.w,a1.x,a1.y,a1.z,a1.w};
        float rb[8] = {b0.x,b0.y,b0.z,b0.w,b1.x,b1.y,b1.z,b1.w};
        float tq = (float)(128 + qrow);
        #pragma unroll
        for (int u = 0; u < 8; ++u) {
            float invf = __expf((float)(8 * g + u) * NLT32);
            float sn, cs; __sincosf(tq * invf, &sn, &cs);
            float a = ra[u] * 0.125f, b = rb[u] * 0.125f;
            qa0[u] = (_Float16)(a * cs - b * sn);
            qa1[u] = (_Float16)(b * cs + a * sn);
        }
    }

    // ---- K staging with RoPE ----
    for (int task = tid; task < 2048; task += BDIM) {
        int j  = task >> 3;
        int cb = (task & 7) << 2;
        int src = ww * 128 - 128 + j;
        float4 x1 = {0.f,0.f,0.f,0.f}, x2 = {0.f,0.f,0.f,0.f};
        if (src >= 0) {
            const float* p = kg + ((size_t)bb * 4096 + src) * 64 + cb;
            x1 = *(const float4*)p;
            x2 = *(const float4*)(p + 32);
        }
        const float* x1p = &x1.x;
        const float* x2p = &x2.x;
        float tj = (float)j;
        #pragma unroll
        for (int u = 0; u < 4; ++u) {
            float invf = __expf((float)(cb + u) * NLT32);
            float sn, cs; __sincosf(tj * invf, &sn, &cs);
            Ks[j][cb + u]      = (_Float16)(x1p[u] * cs - x2p[u] * sn);
            Ks[j][cb + u + 32] = (_Float16)(x2p[u] * cs + x1p[u] * sn);
        }
    }

    // ---- V staging (transposed; pad rows -> 0, masked anyway) ----
    for (int task = tid; task < 4096; task += BDIM) {
        int j  = task >> 4;
        int cb = (task & 15) << 2;
        int src = ww * 128 - 128 + j;
        float4 x = {0.f,0.f,0.f,0.f};
        if (src >= 0)
            x = *(const float4*)(vg + ((size_t)bb * 4096 + src) * 64 + cb);
        const float* xp = &x.x;
        #pragma unroll
        for (int u = 0; u < 4; ++u)
            Vt[cb + u][j] = (_Float16)xp[u];
    }

    __syncthreads();

    // ---- QK^T (swapped): acc[jt] holds D[j = 16*jt+4g+r][i = c] ----
    f32x4 acc[16];
    #pragma unroll
    for (int jt = 0; jt < 16; ++jt) acc[jt] = (f32x4){0.f,0.f,0.f,0.f};

    #pragma unroll
    for (int jt = 0; jt < 16; ++jt) {
        f16x8 kb0 = *(const f16x8*)&Ks[jt * 16 + c][8 * g];
        f16x8 kb1 = *(const f16x8*)&Ks[jt * 16 + c][32 + 8 * g];
        acc[jt] = __builtin_amdgcn_mfma_f32_16x16x32_f16(kb0, qa0, acc[jt], 0, 0, 0);
        acc[jt] = __builtin_amdgcn_mfma_f32_16x16x32_f16(kb1, qa1, acc[jt], 0, 0, 0);
    }

    // ---- mask + softmax over j for row i = c (per-lane + shfl 16,32) ----
    const int i0 = qrow;   // q row in window
    #pragma unroll
    for (int jt = 0; jt < 16; ++jt) {
        #pragma unroll
        for (int r = 0; r < 4; ++r) {
            int j = jt * 16 + 4 * g + r;
            if ((j > i0 + 128) || (w0 && j < 128)) acc[jt][r] = NEG;
        }
    }

    float m = NEG;
    #pragma unroll
    for (int jt = 0; jt < 16; ++jt)
        #pragma unroll
        for (int r = 0; r < 4; ++r) m = fmaxf(m, acc[jt][r]);
    m = fmaxf(m, __shfl_xor(m, 16));
    m = fmaxf(m, __shfl_xor(m, 32));

    float s = 0.f;
    #pragma unroll
    for (int jt = 0; jt < 16; ++jt) {
        #pragma unroll
        for (int r = 0; r < 4; ++r) {
            float p = __expf(acc[jt][r] - m);   // masked -> underflow to 0
            acc[jt][r] = p;
            s += p;
        }
    }
    s += __shfl_xor(s, 16);
    s += __shfl_xor(s, 32);
    float rcp = 1.0f / s;
    #pragma unroll
    for (int jt = 0; jt < 16; ++jt)
        #pragma unroll
        for (int r = 0; r < 4; ++r) acc[jt][r] *= rcp;

    // ---- PV: A = P (regs), B = V with matching j-slot permutation ----
    // step s8: slots u=0..3 -> j = 32*s8 + 4g + u ; u=4..7 -> j = 32*s8 + 16 + 4g + (u-4)
    f32x4 accO[4];
    #pragma unroll
    for (int nt = 0; nt < 4; ++nt) accO[nt] = (f32x4){0.f,0.f,0.f,0.f};

    #pragma unroll
    for (int s8 = 0; s8 < 8; ++s8) {
        f16x8 pa;
        #pragma unroll
        for (int r = 0; r < 4; ++r) {
            pa[r]     = (_Float16)acc[2 * s8][r];
            pa[r + 4] = (_Float16)acc[2 * s8 + 1][r];
        }
        #pragma unroll
        for (int nt = 0; nt < 4; ++nt) {
            f16x4 vb0 = *(const f16x4*)&Vt[nt * 16 + c][s8 * 32 + 4 * g];
            f16x4 vb1 = *(const f16x4*)&Vt[nt * 16 + c][s8 * 32 + 16 + 4 * g];
            f16x8 vb;
            #pragma unroll
            for (int u = 0; u < 4; ++u) { vb[u] = vb0[u]; vb[u + 4] = vb1[u]; }
            accO[nt] = __builtin_amdgcn_mfma_f32_16x16x32_f16(pa, vb, accO[nt], 0, 0, 0);
        }
    }

    // ---- store: D[m = i][n = e]: lane (g,c) -> i = wv*16 + 4g + r, e = 16*nt + c ----
    float* op = outg + qbase + (size_t)(wv * 16) * 64;
    #pragma unroll
    for (int nt = 0; nt < 4; ++nt)
        #pragma unroll
        for (int r = 0; r < 4; ++r)
            op[(size_t)(4 * g + r) * 64 + nt * 16 + c] = accO[nt][r];
}

extern "C" void kernel_launch(void* const* d_in, const int* in_sizes, int n_in,
                              void* d_out, int out_size, void* d_ws, size_t ws_size,
                              hipStream_t stream) {
    (void)in_sizes; (void)n_in; (void)out_size; (void)d_ws; (void)ws_size;
    const float* q = (const float*)d_in[0];
    const float* k = (const float*)d_in[1];
    const float* v = (const float*)d_in[2];
    float* out = (float*)d_out;
    dim3 grid(32, 32);  // x = window, y = batch
    la_kernel<<<grid, BDIM, 0, stream>>>(q, k, v, out);
}